// Round 5
// baseline (290.488 us; speedup 1.0000x reference)
//
#include <hip/hip_runtime.h>
#include <hip/hip_cooperative_groups.h>

namespace cg = cooperative_groups;

typedef __attribute__((ext_vector_type(8))) short bf8_t;   // 8 bf16 (4 VGPRs)
typedef __attribute__((ext_vector_type(4))) float f4_t;

#define KTOP  2
#define NPAIR 16
#define EPSV  1e-5f
#define XSTR  40     // padded elems per (row,col) cell: 80 B -> near-uniform LDS banks

// ws layout (float units):
//  xtp   (ushort): 16*66*66*40 = 2,787,840 us -> 1,393,920 f
//  wTb   (ushort): 8*9*256*32  =   589,824 us ->   294,912 f
//  stats (float) : 16*8*2      =         256 f
#define OFF_XTP   0
#define OFF_WTB   1393920
#define OFF_STATS (1393920 + 294912)

__device__ __forceinline__ unsigned short f2bf(float f) {
    unsigned u = __builtin_bit_cast(unsigned, f);
    u = (u + 0x7FFFu + ((u >> 16) & 1u)) >> 16;
    return (unsigned short)u;
}

union SharedU {
    float wsh[32 * 288];                       // 36864 B (prep-w)
    float xt[2][32][65];                       // 16640 B (prep-x, 2 halves)
    struct {
        short  xs[2][4 * 66 * XSTR];           // 42240 B (conv x tiles, both k)
        float2 gab[2][256];                    //  4096 B (GN coeffs)
    } c;                                       // 46336 B total
};

// ---------------------------------------------------------------------------
// One cooperative kernel: prep -> grid.sync -> conv(+stats) -> grid.sync ->
// GN+SiLU+combine+store. Conv computed ONCE; acc lives in VGPRs across sync.
// Block = (st=blk&31: 2 image rows) x (b=blk>>5). 8 waves: 4 cout x 2 row.
// ---------------------------------------------------------------------------
__launch_bounds__(512, 2)
__global__ void fused(const float* __restrict__ x, const float* __restrict__ w,
                      const int* __restrict__ ridx, const float* __restrict__ rw,
                      const float* __restrict__ gamma, const float* __restrict__ beta,
                      unsigned short* __restrict__ xtp, unsigned short* __restrict__ wTb,
                      float* __restrict__ stats, float* __restrict__ out)
{
    __shared__ SharedU sh;
    const int tid = threadIdx.x;
    const int blk = blockIdx.x;

    // ---------------- Phase A: prep (grid-strided over 592 units) ----------
    if (blk == 0 && tid < NPAIR * 8 * 2) stats[tid] = 0.f;
    for (int u = blk; u < 592; u += 256) {
        __syncthreads();                      // protect LDS reuse across units
        if (u < 64) {
            // conv_w [e*256+c][i(32)][tap(9)] fp32 -> wTb[e][tap][cout][i] bf16
            const int e = u >> 3, cb = (u & 7) * 32;
            const float4* src = (const float4*)(w + (size_t)(e * 256 + cb) * 288);
            for (int f = tid; f < 2304; f += 512) ((float4*)sh.wsh)[f] = src[f];
            __syncthreads();
            for (int idx = tid; idx < 9216; idx += 512) {
                int tap = idx >> 10, rem = idx & 1023, cc = rem >> 5, i = rem & 31;
                wTb[((size_t)(e * 9 + tap) * 256 + cb + cc) * 32 + i] =
                    f2bf(sh.wsh[cc * 288 + i * 9 + tap]);
            }
        } else {
            // x gather+transpose -> xtp[p][row66][col66][XSTR]; 2 rows per block
            const int v = u - 64;             // 0..527
            const int p = v / 33, rp = v - p * 33;
            const int h = tid >> 8, ht = tid & 255;
            const int r = rp * 2 + h;         // 0..65 padded row
            const int b = p >> 1, e = ridx[p];
            const bool inter = (r >= 1 && r <= 64);
            if (inter) {
                const float* xb = x + (((size_t)b * 256 + e * 32) * 64 + (r - 1)) * 64;
                for (int f = ht; f < 2048; f += 256)
                    sh.xt[h][f >> 6][f & 63] = xb[(size_t)(f >> 6) * 4096 + (f & 63)];
            }
            __syncthreads();
            unsigned short* ob = xtp + ((size_t)p * 66 + r) * (66 * XSTR);
            for (int f = ht; f < 1056; f += 256) {    // 66 cols x 16 ch-pairs
                int c = f >> 4, chp = f & 15;
                ushort2 vv = make_ushort2(0, 0);
                if (inter && c >= 1 && c <= 64)
                    vv = make_ushort2(f2bf(sh.xt[h][2 * chp][c - 1]),
                                      f2bf(sh.xt[h][2 * chp + 1][c - 1]));
                *(ushort2*)(ob + c * XSTR + chp * 2) = vv;
            }
        }
    }
    __threadfence();
    cg::this_grid().sync();

    // ---------------- Phase B: conv once (A=w, B=x), stats ----------------
    const int st = blk & 31;                  // 0..31 (2 image rows)
    const int b  = blk >> 5;                  // 0..7

    {   // stage x tiles for both pairs (linear 42 KB copy)
        const unsigned short* g0 = xtp + ((size_t)(b * KTOP + 0) * 66 + st * 2) * (66 * XSTR);
        const unsigned short* g1 = xtp + ((size_t)(b * KTOP + 1) * 66 + st * 2) * (66 * XSTR);
        for (int f = tid; f < 2640; f += 512) {
            const unsigned short* s = (f < 1320) ? (g0 + f * 8) : (g1 + (f - 1320) * 8);
            *(bf8_t*)&sh.c.xs[0][f * 8] = *(const bf8_t*)s;
        }
    }
    __syncthreads();

    const int lane = tid & 63, l15 = lane & 15, oct = lane >> 4;
    const int wave = tid >> 6, wc = wave & 3, wsp = wave >> 2;

    f4_t acc[2][4][4];
    #pragma unroll
    for (int k = 0; k < 2; ++k)
        #pragma unroll
        for (int mi = 0; mi < 4; ++mi)
            #pragma unroll
            for (int ni = 0; ni < 4; ++ni)
                acc[k][mi][ni] = (f4_t){0.f, 0.f, 0.f, 0.f};

    #pragma unroll
    for (int k = 0; k < 2; ++k) {
        const int e = ridx[b * 2 + k];
        const unsigned short* Ab = wTb + ((size_t)e * 9 * 256 + wc * 64 + l15) * 32 + oct * 8;
        const short* Bb = &sh.c.xs[k][0] + (wsp * 66 + l15) * XSTR + oct * 8;
        #pragma unroll
        for (int tap = 0; tap < 9; ++tap) {
            const int dy = tap / 3, dx = tap % 3;
            bf8_t aw[4], bx[4];
            #pragma unroll
            for (int mi = 0; mi < 4; ++mi)
                aw[mi] = *(const bf8_t*)(Ab + tap * 8192 + mi * 512);
            #pragma unroll
            for (int ni = 0; ni < 4; ++ni)
                bx[ni] = *(const bf8_t*)(Bb + (dy * 66 + ni * 16 + dx) * XSTR);
            #pragma unroll
            for (int mi = 0; mi < 4; ++mi)
                #pragma unroll
                for (int ni = 0; ni < 4; ++ni)
                    acc[k][mi][ni] = __builtin_amdgcn_mfma_f32_16x16x32_bf16(
                        aw[mi], bx[ni], acc[k][mi][ni], 0, 0, 0);
        }
    }

    // GN partial stats: group g = wc*2 + (mi>=2); separate per k
    float sv[2][2] = {{0.f, 0.f}, {0.f, 0.f}};
    float qv[2][2] = {{0.f, 0.f}, {0.f, 0.f}};
    #pragma unroll
    for (int k = 0; k < 2; ++k)
        #pragma unroll
        for (int mi = 0; mi < 4; ++mi) {
            const int hf = mi >> 1;
            #pragma unroll
            for (int ni = 0; ni < 4; ++ni)
                #pragma unroll
                for (int r = 0; r < 4; ++r) {
                    float vv = acc[k][mi][ni][r];
                    sv[k][hf] += vv;
                    qv[k][hf] = fmaf(vv, vv, qv[k][hf]);
                }
        }
    #pragma unroll
    for (int m = 32; m >= 1; m >>= 1)
        #pragma unroll
        for (int k = 0; k < 2; ++k)
            #pragma unroll
            for (int hf = 0; hf < 2; ++hf) {
                sv[k][hf] += __shfl_xor(sv[k][hf], m);
                qv[k][hf] += __shfl_xor(qv[k][hf], m);
            }
    if (lane == 0) {
        #pragma unroll
        for (int k = 0; k < 2; ++k)
            #pragma unroll
            for (int hf = 0; hf < 2; ++hf) {
                int p = b * 2 + k, g = wc * 2 + hf;
                atomicAdd(&stats[(p * 8 + g) * 2 + 0], sv[k][hf]);
                atomicAdd(&stats[(p * 8 + g) * 2 + 1], qv[k][hf]);
            }
    }
    __threadfence();
    cg::this_grid().sync();

    // ---------------- Phase D: GN + SiLU + combine + store ----------------
    {   // per-cout coefficients: ga = gamma*inv, be = beta - mu*ga
        int k = tid >> 8, c = tid & 255;
        int p = b * 2 + k, e = ridx[p], g = c >> 5;
        float s = stats[(p * 8 + g) * 2 + 0];
        float q = stats[(p * 8 + g) * 2 + 1];
        const float cnt = 1.f / 131072.f;
        float mu  = s * cnt;
        float var = fmaf(-mu, mu, q * cnt);
        float inv = rsqrtf(var + EPSV);
        float ga  = gamma[e * 256 + c] * inv;
        float be  = fmaf(-mu, ga, beta[e * 256 + c]);
        sh.c.gab[k][c] = make_float2(ga, be);
    }
    __syncthreads();

    const float wk0 = rw[b * 2 + 0];
    const float wk1 = rw[b * 2 + 1];
    #pragma unroll
    for (int mi = 0; mi < 4; ++mi) {
        float2 g0[4], g1[4];
        #pragma unroll
        for (int r = 0; r < 4; ++r) {
            g0[r] = sh.c.gab[0][wc * 64 + mi * 16 + oct * 4 + r];
            g1[r] = sh.c.gab[1][wc * 64 + mi * 16 + oct * 4 + r];
        }
        #pragma unroll
        for (int ni = 0; ni < 4; ++ni)
            #pragma unroll
            for (int r = 0; r < 4; ++r) {
                float n0  = fmaf(acc[0][mi][ni][r], g0[r].x, g0[r].y);
                float sg0 = __builtin_amdgcn_rcpf(1.f + __expf(-n0));
                acc[0][mi][ni][r] = wk0 * n0 * sg0;       // overwrite: k=0 term
                float n1  = fmaf(acc[1][mi][ni][r], g1[r].x, g1[r].y);
                float sg1 = __builtin_amdgcn_rcpf(1.f + __expf(-n1));
                acc[0][mi][ni][r] = fmaf(wk1 * n1, sg1, acc[0][mi][ni][r]);
            }
    }

    const int row = st * 2 + wsp;
    #pragma unroll
    for (int mi = 0; mi < 4; ++mi)
        #pragma unroll
        for (int r = 0; r < 4; ++r) {
            float* ob = out + ((size_t)(b * 256 + wc * 64 + mi * 16 + oct * 4 + r)) * 4096
                            + row * 64 + l15;
            #pragma unroll
            for (int ni = 0; ni < 4; ++ni)
                ob[ni * 16] = acc[0][mi][ni][r];
        }
}

// ---------------------------------------------------------------------------
extern "C" void kernel_launch(void* const* d_in, const int* in_sizes, int n_in,
                              void* d_out, int out_size, void* d_ws, size_t ws_size,
                              hipStream_t stream) {
    const float* x      = (const float*)d_in[0];
    const float* rw     = (const float*)d_in[1];
    const int*   ridx   = (const int*)  d_in[2];
    const float* conv_w = (const float*)d_in[4];
    const float* gamma  = (const float*)d_in[5];
    const float* beta   = (const float*)d_in[6];
    float* out = (float*)d_out;

    float* ws = (float*)d_ws;
    unsigned short* xtp   = (unsigned short*)(ws + OFF_XTP);
    unsigned short* wTb   = (unsigned short*)(ws + OFF_WTB);
    float*          stats = ws + OFF_STATS;

    void* args[] = {(void*)&x, (void*)&conv_w, (void*)&ridx, (void*)&rw,
                    (void*)&gamma, (void*)&beta, (void*)&xtp, (void*)&wTb,
                    (void*)&stats, (void*)&out};
    hipLaunchCooperativeKernel((const void*)fused, dim3(256), dim3(512),
                               args, 0, stream);
}

// Round 8
// 194.815 us; speedup vs baseline: 1.4911x; 1.4911x over previous
//
#include <hip/hip_runtime.h>
#include <hip/hip_cooperative_groups.h>

namespace cg = cooperative_groups;

typedef __attribute__((ext_vector_type(8))) short bf8_t;   // 8 bf16 (4 VGPRs)
typedef __attribute__((ext_vector_type(4))) float f4_t;

#define EPSV 1e-5f
#define XSTR 40      // padded elems per (row,col) cell: 80 B

// ws layout (float units):
//  wTb   (ushort): 8*9*256*32 = 589,824 us -> 294,912 f
//  stats (float) : 16*8*2 = 256 f
#define OFF_STATS 294912

__device__ __forceinline__ unsigned short f2bf(float f) {
    unsigned u = __builtin_bit_cast(unsigned, f);
    u = (u + 0x7FFFu + ((u >> 16) & 1u)) >> 16;
    return (unsigned short)u;
}

// ---------------------------------------------------------------------------
// prep_w: conv_w [e*256+c][i(32)][tap(9)] fp32 -> wTb[e][tap][cout][i] bf16.
// Block = (e, 32 couts); 64 blocks. Block 0 zeroes stats.
// ---------------------------------------------------------------------------
__global__ void prep_w(const float* __restrict__ w, unsigned short* __restrict__ wTb,
                       float* __restrict__ stats) {
    __shared__ float ls[32 * 288];
    const int tid = threadIdx.x;
    const int e   = blockIdx.x >> 3;
    const int cb  = (blockIdx.x & 7) * 32;
    if (blockIdx.x == 0 && tid < 256) stats[tid] = 0.f;
    const float4* src = (const float4*)(w + (size_t)(e * 256 + cb) * 288);
    for (int f = tid; f < 2304; f += 256) ((float4*)ls)[f] = src[f];
    __syncthreads();
    for (int idx = tid; idx < 9216; idx += 256) {
        int tap = idx >> 10, rem = idx & 1023, cc = rem >> 5, i = rem & 31;
        wTb[((size_t)(e * 9 + tap) * 256 + cb + cc) * 32 + i] =
            f2bf(ls[cc * 288 + i * 9 + tap]);
    }
}

// ---------------------------------------------------------------------------
// fconv (cooperative, grid=256 = 1 block/CU — the config PROVEN to launch in
// round 5). Block = (b = blk>>5, row-pair st = blk&31 -> rows r0=2st, r0+1).
// Stage x rows r0-1..r0+2 (both pairs) straight from global fp32 -> LDS bf16.
// Conv ONCE per k into f32 acc[4][4] (64 regs), take GN stats, pack to bf16
// (64 packed regs persist across grid.sync -> no spill at the 256-VGPR cap).
// grid.sync. GN coeffs from stats (LDS), SiLU+combine, coalesced dword stores.
// 8 waves: 4 cout-waves x 2 row-waves.
// ---------------------------------------------------------------------------
__launch_bounds__(512, 2)
__global__ void fconv(const float* __restrict__ x,
                      const unsigned short* __restrict__ wTb,
                      const int* __restrict__ ridx, const float* __restrict__ rw,
                      const float* __restrict__ gamma, const float* __restrict__ beta,
                      float* __restrict__ stats, float* __restrict__ out)
{
    __shared__ unsigned short xs[2 * 4 * 66 * XSTR];   // 42240 B
    __shared__ float2 gab[2][256];                     //  4096 B

    const int tid = threadIdx.x;
    const int blk = blockIdx.x;
    const int st  = blk & 31;
    const int b   = blk >> 5;
    const int r0  = st * 2;
    const int e0  = ridx[b * 2 + 0];
    const int e1  = ridx[b * 2 + 1];

    // ---- stage x window: 2 pairs x 4 padded rows x 66 cols x 32 ch ----
    {   // col-halo zeros: 2k x 4rows x 2sides x 32ch = 512
        int ch = tid & 31, side = (tid >> 5) & 1, t2 = tid >> 6;   // t2 = k*4+rowi
        xs[(t2 * 66 + side * 65) * XSTR + ch] = 0;
    }
    for (int u = tid; u < 4096; u += 512) {     // (k,rowi,ch,c4) float4 units
        int c4 = u & 15, ch = (u >> 4) & 31, t2 = u >> 9;   // t2 = k*4+rowi
        int k = t2 >> 2, rowi = t2 & 3;
        int e = k ? e1 : e0;
        int gr = r0 - 1 + rowi;
        float4 v = make_float4(0.f, 0.f, 0.f, 0.f);
        if ((unsigned)gr < 64u)
            v = *(const float4*)&x[(((size_t)b * 256 + e * 32 + ch) * 64 + gr) * 64 + c4 * 4];
        int base = (t2 * 66 + 1 + c4 * 4) * XSTR + ch;
        xs[base]            = f2bf(v.x);
        xs[base + XSTR]     = f2bf(v.y);
        xs[base + 2 * XSTR] = f2bf(v.z);
        xs[base + 3 * XSTR] = f2bf(v.w);
    }
    __syncthreads();

    const int lane = tid & 63, l15 = lane & 15, oct = lane >> 4;
    const int wave = tid >> 6, wc = wave & 3, wsp = wave >> 2;

    unsigned pk[2][4][4][2];              // [k][mi][ni][pair] packed bf16x2
    float sv[2][2], qv[2][2];
    #pragma unroll
    for (int k = 0; k < 2; ++k) { sv[k][0] = sv[k][1] = qv[k][0] = qv[k][1] = 0.f; }

    #pragma unroll
    for (int k = 0; k < 2; ++k) {
        const int e = k ? e1 : e0;
        const unsigned short* Ab = wTb + ((size_t)e * 9 * 256 + wc * 64 + l15) * 32 + oct * 8;
        const unsigned short* Bb = xs + (((k * 4 + wsp) * 66) + l15) * XSTR + oct * 8;

        f4_t acc[4][4];
        #pragma unroll
        for (int mi = 0; mi < 4; ++mi)
            #pragma unroll
            for (int ni = 0; ni < 4; ++ni)
                acc[mi][ni] = (f4_t){0.f, 0.f, 0.f, 0.f};

        #pragma unroll
        for (int tap = 0; tap < 9; ++tap) {
            const int dy = tap / 3, dx = tap % 3;
            bf8_t aw[4], bx[4];
            #pragma unroll
            for (int mi = 0; mi < 4; ++mi)
                aw[mi] = *(const bf8_t*)(Ab + tap * 8192 + mi * 512);
            #pragma unroll
            for (int ni = 0; ni < 4; ++ni)
                bx[ni] = *(const bf8_t*)(Bb + (dy * 66 + ni * 16 + dx) * XSTR);
            #pragma unroll
            for (int mi = 0; mi < 4; ++mi)
                #pragma unroll
                for (int ni = 0; ni < 4; ++ni)
                    acc[mi][ni] = __builtin_amdgcn_mfma_f32_16x16x32_bf16(
                        aw[mi], bx[ni], acc[mi][ni], 0, 0, 0);
        }

        // stats from f32 acc, then pack to bf16 pairs (frees the f32 regs)
        #pragma unroll
        for (int mi = 0; mi < 4; ++mi) {
            const int hf = mi >> 1;
            #pragma unroll
            for (int ni = 0; ni < 4; ++ni) {
                float a0 = acc[mi][ni][0], a1 = acc[mi][ni][1];
                float a2 = acc[mi][ni][2], a3 = acc[mi][ni][3];
                sv[k][hf] += a0 + a1 + a2 + a3;
                qv[k][hf] = fmaf(a0, a0, fmaf(a1, a1, fmaf(a2, a2, fmaf(a3, a3, qv[k][hf]))));
                pk[k][mi][ni][0] = (unsigned)f2bf(a0) | ((unsigned)f2bf(a1) << 16);
                pk[k][mi][ni][1] = (unsigned)f2bf(a2) | ((unsigned)f2bf(a3) << 16);
            }
        }
    }

    #pragma unroll
    for (int m = 32; m >= 1; m >>= 1)
        #pragma unroll
        for (int k = 0; k < 2; ++k)
            #pragma unroll
            for (int hf = 0; hf < 2; ++hf) {
                sv[k][hf] += __shfl_xor(sv[k][hf], m);
                qv[k][hf] += __shfl_xor(qv[k][hf], m);
            }
    if (lane == 0) {
        #pragma unroll
        for (int k = 0; k < 2; ++k)
            #pragma unroll
            for (int hf = 0; hf < 2; ++hf) {
                int p = b * 2 + k, g = wc * 2 + hf;
                atomicAdd(&stats[(p * 8 + g) * 2 + 0], sv[k][hf]);
                atomicAdd(&stats[(p * 8 + g) * 2 + 1], qv[k][hf]);
            }
    }
    __threadfence();
    cg::this_grid().sync();

    // ---- GN coeffs + SiLU + combine + store ----
    {
        int k = tid >> 8, c = tid & 255;
        int p = b * 2 + k, e = ridx[p], g = c >> 5;
        float s = stats[(p * 8 + g) * 2 + 0];
        float q = stats[(p * 8 + g) * 2 + 1];
        const float cnt = 1.f / 131072.f;
        float mu  = s * cnt;
        float var = fmaf(-mu, mu, q * cnt);
        float inv = rsqrtf(var + EPSV);
        float ga  = gamma[e * 256 + c] * inv;
        float be  = fmaf(-mu, ga, beta[e * 256 + c]);
        gab[k][c] = make_float2(ga, be);
    }
    __syncthreads();

    const float wk0 = rw[b * 2 + 0];
    const float wk1 = rw[b * 2 + 1];
    const int row = r0 + wsp;
    #pragma unroll
    for (int mi = 0; mi < 4; ++mi) {
        float2 g0[4], g1[4];
        #pragma unroll
        for (int rr = 0; rr < 4; ++rr) {
            g0[rr] = gab[0][wc * 64 + mi * 16 + oct * 4 + rr];
            g1[rr] = gab[1][wc * 64 + mi * 16 + oct * 4 + rr];
        }
        #pragma unroll
        for (int ni = 0; ni < 4; ++ni)
            #pragma unroll
            for (int rr = 0; rr < 4; ++rr) {
                unsigned p0 = pk[0][mi][ni][rr >> 1];
                unsigned p1 = pk[1][mi][ni][rr >> 1];
                float c0 = __builtin_bit_cast(float, (rr & 1) ? (p0 & 0xFFFF0000u) : (p0 << 16));
                float c1 = __builtin_bit_cast(float, (rr & 1) ? (p1 & 0xFFFF0000u) : (p1 << 16));
                float n0 = fmaf(c0, g0[rr].x, g0[rr].y);
                float n1 = fmaf(c1, g1[rr].x, g1[rr].y);
                float s0 = __builtin_amdgcn_rcpf(1.f + __expf(-n0));
                float s1 = __builtin_amdgcn_rcpf(1.f + __expf(-n1));
                float res = fmaf(wk1 * n1, s1, wk0 * n0 * s0);
                out[((size_t)(b * 256 + wc * 64 + mi * 16 + oct * 4 + rr)) * 4096
                    + row * 64 + ni * 16 + l15] = res;
            }
    }
}

// ---------------------------------------------------------------------------
extern "C" void kernel_launch(void* const* d_in, const int* in_sizes, int n_in,
                              void* d_out, int out_size, void* d_ws, size_t ws_size,
                              hipStream_t stream) {
    const float* x      = (const float*)d_in[0];
    const float* rw     = (const float*)d_in[1];
    const int*   ridx   = (const int*)  d_in[2];
    const float* conv_w = (const float*)d_in[4];
    const float* gamma  = (const float*)d_in[5];
    const float* beta   = (const float*)d_in[6];
    float* out = (float*)d_out;

    float* ws = (float*)d_ws;
    unsigned short* wTb   = (unsigned short*)ws;
    float*          stats = ws + OFF_STATS;

    hipLaunchKernelGGL(prep_w, dim3(64), dim3(256), 0, stream, conv_w, wTb, stats);

    void* args[] = {(void*)&x, (void*)&wTb, (void*)&ridx, (void*)&rw,
                    (void*)&gamma, (void*)&beta, (void*)&stats, (void*)&out};
    hipLaunchCooperativeKernel((const void*)fconv, dim3(256), dim3(512),
                               args, 0, stream);
}

// Round 9
// 160.299 us; speedup vs baseline: 1.8122x; 1.2153x over previous
//
#include <hip/hip_runtime.h>

typedef __attribute__((ext_vector_type(8))) short bf8_t;   // 8 bf16 (4 VGPRs)
typedef __attribute__((ext_vector_type(4))) float f4_t;

#define EPSV 1e-5f
#define XSTR 40      // padded elems per (row,col) cell: 80 B

// ws layout (float units):
//  wTb   (ushort): 8*9*256*32 = 589,824 us -> 294,912 f
//  stats (float) : 16*8*2 = 256 f
#define OFF_STATS 294912

__device__ __forceinline__ unsigned short f2bf(float f) {
    unsigned u = __builtin_bit_cast(unsigned, f);
    u = (u + 0x7FFFu + ((u >> 16) & 1u)) >> 16;
    return (unsigned short)u;
}

// ---------------------------------------------------------------------------
// prep_w: conv_w [e*256+c][i(32)][tap(9)] fp32 -> wTb[e][tap][cout][i] bf16.
// Block = (e, 32 couts); 64 blocks. Block 0 zeroes stats.
// ---------------------------------------------------------------------------
__global__ void prep_w(const float* __restrict__ w, unsigned short* __restrict__ wTb,
                       float* __restrict__ stats) {
    __shared__ float ls[32 * 288];
    const int tid = threadIdx.x;
    const int e   = blockIdx.x >> 3;
    const int cb  = (blockIdx.x & 7) * 32;
    if (blockIdx.x == 0 && tid < 256) stats[tid] = 0.f;
    const float4* src = (const float4*)(w + (size_t)(e * 256 + cb) * 288);
    for (int f = tid; f < 2304; f += 256) ((float4*)ls)[f] = src[f];
    __syncthreads();
    for (int idx = tid; idx < 9216; idx += 256) {
        int tap = idx >> 10, rem = idx & 1023, cc = rem >> 5, i = rem & 31;
        wTb[((size_t)(e * 9 + tap) * 256 + cb + cc) * 32 + i] =
            f2bf(ls[cc * 288 + i * 9 + tap]);
    }
}

// ---------------------------------------------------------------------------
// conv_stats: block = (row r, pair p), 256 thr = 4 cout-waves. Wave tile =
// 64 cout x 64 sp, acc[4][4]. x rows r-1..r+1 staged global->LDS bf16.
// No conv output stored — GN partial sums only. 1024 blocks, 4/CU (50% occ).
// ---------------------------------------------------------------------------
__launch_bounds__(256, 4)
__global__ void conv_stats(const float* __restrict__ x,
                           const unsigned short* __restrict__ wTb,
                           const int* __restrict__ ridx,
                           float* __restrict__ stats)
{
    __shared__ unsigned short xs[3 * 66 * XSTR];   // 15840 B

    const int tid = threadIdx.x;
    const int r   = blockIdx.x;        // 0..63
    const int p   = blockIdx.y;        // 0..15
    const int b   = p >> 1;
    const int e   = ridx[p];

    if (tid < 192) {                   // col-halo zeros: 3 rows x 2 sides x 32 ch
        int ch = tid & 31, side = (tid >> 5) & 1, rowi = tid >> 6;
        xs[(rowi * 66 + side * 65) * XSTR + ch] = 0;
    }
    for (int u = tid; u < 1536; u += 256) {   // (rowi,ch,c4) float4 units
        int c4 = u & 15, ch = (u >> 4) & 31, rowi = u >> 9;
        int gr = r - 1 + rowi;
        float4 v = make_float4(0.f, 0.f, 0.f, 0.f);
        if ((unsigned)gr < 64u)
            v = *(const float4*)&x[(((size_t)b * 256 + e * 32 + ch) * 64 + gr) * 64 + c4 * 4];
        int base = (rowi * 66 + 1 + c4 * 4) * XSTR + ch;
        xs[base]            = f2bf(v.x);
        xs[base + XSTR]     = f2bf(v.y);
        xs[base + 2 * XSTR] = f2bf(v.z);
        xs[base + 3 * XSTR] = f2bf(v.w);
    }
    __syncthreads();

    const int lane = tid & 63, l15 = lane & 15, oct = lane >> 4;
    const int wc   = tid >> 6;         // cout-wave 0..3

    const unsigned short* Ab = wTb + ((size_t)e * 2304 + wc * 64 + l15) * 32 + oct * 8;
    const unsigned short* Bb = xs + l15 * XSTR + oct * 8;

    f4_t acc[4][4];
    #pragma unroll
    for (int mi = 0; mi < 4; ++mi)
        #pragma unroll
        for (int ni = 0; ni < 4; ++ni)
            acc[mi][ni] = (f4_t){0.f, 0.f, 0.f, 0.f};

    #pragma unroll
    for (int tap = 0; tap < 9; ++tap) {
        const int dy = tap / 3, dx = tap % 3;
        bf8_t aw[4], bx[4];
        #pragma unroll
        for (int mi = 0; mi < 4; ++mi)
            aw[mi] = *(const bf8_t*)(Ab + tap * 8192 + mi * 512);
        #pragma unroll
        for (int ni = 0; ni < 4; ++ni)
            bx[ni] = *(const bf8_t*)(Bb + (dy * 66 + ni * 16 + dx) * XSTR);
        #pragma unroll
        for (int mi = 0; mi < 4; ++mi)
            #pragma unroll
            for (int ni = 0; ni < 4; ++ni)
                acc[mi][ni] = __builtin_amdgcn_mfma_f32_16x16x32_bf16(
                    aw[mi], bx[ni], acc[mi][ni], 0, 0, 0);
    }

    float sv[2] = {0.f, 0.f}, qv[2] = {0.f, 0.f};
    #pragma unroll
    for (int mi = 0; mi < 4; ++mi) {
        const int hf = mi >> 1;
        #pragma unroll
        for (int ni = 0; ni < 4; ++ni)
            #pragma unroll
            for (int rr = 0; rr < 4; ++rr) {
                float v = acc[mi][ni][rr];
                sv[hf] += v;
                qv[hf] = fmaf(v, v, qv[hf]);
            }
    }
    #pragma unroll
    for (int m = 32; m >= 1; m >>= 1)
        #pragma unroll
        for (int hf = 0; hf < 2; ++hf) {
            sv[hf] += __shfl_xor(sv[hf], m);
            qv[hf] += __shfl_xor(qv[hf], m);
        }
    if (lane == 0) {
        #pragma unroll
        for (int hf = 0; hf < 2; ++hf) {
            int g = wc * 2 + hf;
            atomicAdd(&stats[(p * 8 + g) * 2 + 0], sv[hf]);
            atomicAdd(&stats[(p * 8 + g) * 2 + 1], qv[hf]);
        }
    }
}

// ---------------------------------------------------------------------------
// conv_apply: block = (row r, cout-half, batch b), 256 thr = 4 waves
// (2 cout-waves x 2 sp-half-waves). Recomputes conv for both k; k=0's acc is
// folded into SiLU-weighted res before k=1 (peak regs ~110). Coalesced dword
// stores to out. 1024 blocks, 4/CU.
// ---------------------------------------------------------------------------
__launch_bounds__(256, 4)
__global__ void conv_apply(const float* __restrict__ x,
                           const unsigned short* __restrict__ wTb,
                           const int* __restrict__ ridx, const float* __restrict__ rw,
                           const float* __restrict__ gamma, const float* __restrict__ beta,
                           const float* __restrict__ stats, float* __restrict__ out)
{
    __shared__ unsigned short xs[2 * 3 * 66 * XSTR];   // 31680 B
    __shared__ float2 gab[2][128];                     //  2048 B

    const int tid  = threadIdx.x;
    const int r    = blockIdx.x;       // 0..63
    const int half = blockIdx.y;       // 0..1 (couts half*128)
    const int b    = blockIdx.z;       // 0..7
    const int e0   = ridx[b * 2 + 0];
    const int e1   = ridx[b * 2 + 1];

    for (int z = tid; z < 384; z += 256) {   // col-halo zeros: 2k x 3rows x 2sides x 32ch
        int ch = z & 31, side = (z >> 5) & 1, t2 = z >> 6;   // t2 = k*3+rowi
        xs[(t2 * 66 + side * 65) * XSTR + ch] = 0;
    }
    for (int u = tid; u < 3072; u += 256) {   // (k,rowi,ch,c4) float4 units
        int c4 = u & 15, ch = (u >> 4) & 31, t2 = u >> 9;
        int k = t2 / 3, rowi = t2 - k * 3;
        int e = k ? e1 : e0;
        int gr = r - 1 + rowi;
        float4 v = make_float4(0.f, 0.f, 0.f, 0.f);
        if ((unsigned)gr < 64u)
            v = *(const float4*)&x[(((size_t)b * 256 + e * 32 + ch) * 64 + gr) * 64 + c4 * 4];
        int base = (t2 * 66 + 1 + c4 * 4) * XSTR + ch;
        xs[base]            = f2bf(v.x);
        xs[base + XSTR]     = f2bf(v.y);
        xs[base + 2 * XSTR] = f2bf(v.z);
        xs[base + 3 * XSTR] = f2bf(v.w);
    }
    {   // GN coefficients for this block's 128 couts x 2 k
        int k = tid >> 7, cl = tid & 127, c = half * 128 + cl;
        int p = b * 2 + k, e = ridx[p], g = c >> 5;
        float s = stats[(p * 8 + g) * 2 + 0];
        float q = stats[(p * 8 + g) * 2 + 1];
        const float cnt = 1.f / 131072.f;
        float mu  = s * cnt;
        float var = fmaf(-mu, mu, q * cnt);
        float inv = rsqrtf(var + EPSV);
        float ga  = gamma[e * 256 + c] * inv;
        float be  = fmaf(-mu, ga, beta[e * 256 + c]);
        gab[k][cl] = make_float2(ga, be);
    }
    __syncthreads();

    const int lane = tid & 63, l15 = lane & 15, oct = lane >> 4;
    const int wave = tid >> 6;
    const int wc2  = wave & 1;         // cout-wave within the 128 (64 couts)
    const int wsp  = wave >> 1;        // sp half (cols wsp*32..+31)

    f4_t res[4][2];
    #pragma unroll
    for (int mi = 0; mi < 4; ++mi)
        #pragma unroll
        for (int ni = 0; ni < 2; ++ni)
            res[mi][ni] = (f4_t){0.f, 0.f, 0.f, 0.f};

    #pragma unroll
    for (int k = 0; k < 2; ++k) {
        const int e = k ? e1 : e0;
        const float wk = rw[b * 2 + k];
        const unsigned short* Ab =
            wTb + ((size_t)e * 2304 + half * 128 + wc2 * 64 + l15) * 32 + oct * 8;
        const unsigned short* Bb = xs + (k * 198 + wsp * 32 + l15) * XSTR + oct * 8;

        f4_t acc[4][2];
        #pragma unroll
        for (int mi = 0; mi < 4; ++mi)
            #pragma unroll
            for (int ni = 0; ni < 2; ++ni)
                acc[mi][ni] = (f4_t){0.f, 0.f, 0.f, 0.f};

        #pragma unroll
        for (int tap = 0; tap < 9; ++tap) {
            const int dy = tap / 3, dx = tap % 3;
            bf8_t aw[4], bx[2];
            #pragma unroll
            for (int mi = 0; mi < 4; ++mi)
                aw[mi] = *(const bf8_t*)(Ab + tap * 8192 + mi * 512);
            #pragma unroll
            for (int ni = 0; ni < 2; ++ni)
                bx[ni] = *(const bf8_t*)(Bb + (dy * 66 + ni * 16 + dx) * XSTR);
            #pragma unroll
            for (int mi = 0; mi < 4; ++mi)
                #pragma unroll
                for (int ni = 0; ni < 2; ++ni)
                    acc[mi][ni] = __builtin_amdgcn_mfma_f32_16x16x32_bf16(
                        aw[mi], bx[ni], acc[mi][ni], 0, 0, 0);
        }

        // fold this k into res (frees acc before next k)
        #pragma unroll
        for (int mi = 0; mi < 4; ++mi) {
            float2 gb[4];
            #pragma unroll
            for (int rr = 0; rr < 4; ++rr)
                gb[rr] = gab[k][wc2 * 64 + mi * 16 + oct * 4 + rr];
            #pragma unroll
            for (int ni = 0; ni < 2; ++ni)
                #pragma unroll
                for (int rr = 0; rr < 4; ++rr) {
                    float n  = fmaf(acc[mi][ni][rr], gb[rr].x, gb[rr].y);
                    float sg = __builtin_amdgcn_rcpf(1.f + __expf(-n));
                    res[mi][ni][rr] = fmaf(wk * n, sg, res[mi][ni][rr]);
                }
        }
    }

    #pragma unroll
    for (int mi = 0; mi < 4; ++mi)
        #pragma unroll
        for (int rr = 0; rr < 4; ++rr) {
            float* ob = out + ((size_t)(b * 256 + half * 128 + wc2 * 64 + mi * 16
                                        + oct * 4 + rr)) * 4096
                            + r * 64 + wsp * 32 + l15;
            #pragma unroll
            for (int ni = 0; ni < 2; ++ni)
                ob[ni * 16] = res[mi][ni][rr];
        }
}

// ---------------------------------------------------------------------------
extern "C" void kernel_launch(void* const* d_in, const int* in_sizes, int n_in,
                              void* d_out, int out_size, void* d_ws, size_t ws_size,
                              hipStream_t stream) {
    const float* x      = (const float*)d_in[0];
    const float* rw     = (const float*)d_in[1];
    const int*   ridx   = (const int*)  d_in[2];
    const float* conv_w = (const float*)d_in[4];
    const float* gamma  = (const float*)d_in[5];
    const float* beta   = (const float*)d_in[6];
    float* out = (float*)d_out;

    float* ws = (float*)d_ws;
    unsigned short* wTb   = (unsigned short*)ws;
    float*          stats = ws + OFF_STATS;

    hipLaunchKernelGGL(prep_w, dim3(64), dim3(256), 0, stream, conv_w, wTb, stats);
    hipLaunchKernelGGL(conv_stats, dim3(64, 16), dim3(256), 0, stream,
                       x, wTb, ridx, stats);
    hipLaunchKernelGGL(conv_apply, dim3(64, 2, 8), dim3(256), 0, stream,
                       x, wTb, ridx, rw, gamma, beta, stats, out);
}